// Round 1
// baseline (105.928 us; speedup 1.0000x reference)
//
#include <hip/hip_runtime.h>
#include <math.h>

#define BIGV  1.0e8f
#define PLANE (512 * 512)            // 262144
#define NTOT  (8 * PLANE)            // 2097152
#define PROWS 640                    // 64 pad + 512 + 64 pad
#define PSTRIDE (PROWS * 512)        // ushorts per padded plane
#define HSENT 1023                   // row-DT sentinel: 1023^2 = 1046529 > max real d2 (511^2+511^2+49)

// ---------------------------------------------------------------------------
// Kernel 1: 1-D DT along axis 3 (binary input) via ballot-built 512-bit line
// mask + clz/ffs nearest-set-bit. Writes h (row distance, USHORT — halves the
// HBM write vs the old f32 h^2) into a PADDED plane layout: row i2 lives at
// (64+i2); rows 0..63 and 576..639 are HSENT pads. Blocks >= 4096 write pads.
// NO atomics anywhere (device-scope atomics cost ~25 us in L2
// writeback/invalidate on gfx950 — measured R5/R8/R9 of prior session).
// ---------------------------------------------------------------------------
__global__ __launch_bounds__(512) void dt_axis3(const int* __restrict__ y,
                                                unsigned short* __restrict__ g1u) {
    int blk = blockIdx.x;
    if (blk >= 4096) {                                 // pad writer: 1024 blocks
        int idx = (blk - 4096) * 512 + threadIdx.x;    // [0, 524288)
        int plane = idx >> 16;
        int rem   = idx & 65535;
        int r     = rem >> 9;                          // 0..127
        int c     = rem & 511;
        int row   = (r < 64) ? r : (r + 512);          // 0..63 or 576..639
        g1u[plane * PSTRIDE + row * 512 + c] = HSENT;
        return;
    }
    __shared__ unsigned long long words[8];
    int i = threadIdx.x;                               // position in line
    int e = blk * 512 + i;                             // y index (lines contiguous)
    unsigned long long bal = __ballot(y[e] != 0);
    int wid  = i >> 6;
    int lane = i & 63;
    if (lane == 0) words[wid] = bal;
    __syncthreads();

    int k = wid, b = lane;
    int dr = 1 << 30;
    {
        unsigned long long m0 = words[k] & (~0ull << b);
        if (m0) {
            dr = (__ffsll((long long)m0) - 1) - b;
        } else {
            #pragma unroll
            for (int k2 = 0; k2 < 8; ++k2) {
                if (k2 > k && dr == (1 << 30) && words[k2]) {
                    dr = (k2 << 6) + (__ffsll((long long)words[k2]) - 1) - i;
                }
            }
        }
    }
    int dl = 1 << 30;
    {
        unsigned long long m0 = words[k] & (~0ull >> (63 - b));
        if (m0) {
            dl = b - (63 - __clzll((long long)m0));
        } else {
            #pragma unroll
            for (int k2 = 7; k2 >= 0; --k2) {
                if (k2 < k && dl == (1 << 30) && words[k2]) {
                    dl = i - ((k2 << 6) + 63 - __clzll((long long)words[k2]));
                }
            }
        }
    }
    int d = min(dl, dr);
    int h = min(d, HSENT);                             // 0..511 real, 1023 = "row empty"
    int bb = blk >> 9, i2 = blk & 511;
    g1u[bb * PSTRIDE + (64 + i2) * 512 + i] = (unsigned short)h;
}

// ---------------------------------------------------------------------------
// Kernel 2 (FUSED axis-2 + axis-0 + epilogue): one thread owns one SPATIAL
// pixel across ALL 8 batches. Runs the prefetch-pipelined column scan 8x
// (independent chains → better latency hiding), keeps the 8 D2 values in
// registers, then does the 8x8 batch min-plus + sigmoid(x)*sqrt + double
// partial sums directly. Deletes the 16 MB D2 HBM round trip and one launch.
// Break uses the previous-iteration m — exiting later is always exact.
// Max prefetch radius 64 fits the 64-row pad exactly.
// ---------------------------------------------------------------------------
__device__ inline double wave_reduce_d(double v) {
    #pragma unroll
    for (int off = 32; off > 0; off >>= 1) v += __shfl_down(v, off, 64);
    return v;
}

__global__ __launch_bounds__(256) void dt2_axis0_epilogue(
        const unsigned short* __restrict__ g1u,
        const float* __restrict__ x,
        double* __restrict__ partials) {
    int s  = blockIdx.x * 256 + threadIdx.x;           // spatial [0, PLANE)
    int i2 = s >> 9;                                   // row
    int i3 = s & 511;                                  // col

    float v[8];                                        // D2 per batch (exact small ints)
    #pragma unroll
    for (int bb = 0; bb < 8; ++bb) {
        const unsigned short* base = g1u + bb * PSTRIDE + (64 + i2) * 512 + i3;
        int h0  = base[0];
        float m = (float)(h0 * h0);                    // exact: <= 1023^2 < 2^24
        int au = base[-512];                           // radius-1 candidates
        int ad = base[+512];
        const unsigned short* up = base - 512;
        const unsigned short* dn = base + 512;
        float fr2 = 1.0f, dstep = 3.0f;                // r^2: 1,4,9,... exact
        int r = 1;
        for (; r < 64; ++r) {
            if (fr2 >= m) break;                       // uses prev-iter m: safe
            int hm = min(au, ad);
            float cand = (float)(hm * hm) + fr2;
            au = up[-512]; ad = dn[+512];              // prefetch radius r+1
            up -= 512; dn += 512;
            m = fminf(m, cand);                        // pads are HSENT: never win
            fr2 += dstep; dstep += 2.0f;
        }
        if (r == 64) {                                 // ultra-rare exact tail
            for (; r < 512; ++r) {
                float f2 = (float)(r * r);
                if (f2 >= m) break;
                int upr = i2 - r, dnr = i2 + r;
                if (upr < 0 && dnr >= 512) break;
                if (upr >= 0) {
                    int hh = g1u[bb * PSTRIDE + (64 + upr) * 512 + i3];
                    m = fminf(m, (float)(hh * hh) + f2);
                }
                if (dnr < 512) {
                    int hh = g1u[bb * PSTRIDE + (64 + dnr) * 512 + i3];
                    m = fminf(m, (float)(hh * hh) + f2);
                }
            }
        }
        v[bb] = m;
    }

    // axis-0 (length 8, brute 8x8 min-plus) + sqrt + sigmoid(x)*d, double acc.
    double acc = 0.0;
    #pragma unroll
    for (int b = 0; b < 8; ++b) {
        float m = BIGV;
        #pragma unroll
        for (int bp = 0; bp < 8; ++bp) {
            float db = (float)((b - bp) * (b - bp));   // compile-time const
            m = fminf(m, v[bp] + db);
        }
        float xv  = x[b * PLANE + s];
        float sig = 1.0f / (1.0f + expf(-xv));
        acc += (double)(sig * sqrtf(m));
    }

    __shared__ double lds[4];
    double w = wave_reduce_d(acc);
    int lane = threadIdx.x & 63;
    int wid  = threadIdx.x >> 6;
    if (lane == 0) lds[wid] = w;
    __syncthreads();
    if (wid == 0) {
        double t = (lane < 4) ? lds[lane] : 0.0;
        #pragma unroll
        for (int off = 2; off > 0; off >>= 1) t += __shfl_down(t, off, 64);
        if (lane == 0) partials[blockIdx.x] = t;
    }
}

// ---------------------------------------------------------------------------
// Kernel 3: deterministic final reduce of 1024 block partials. NO atomics.
// ---------------------------------------------------------------------------
__global__ __launch_bounds__(256) void finalize(const double* __restrict__ partials,
                                                float* __restrict__ out) {
    double a = 0.0;
    for (int i = threadIdx.x; i < 1024; i += 256) a += partials[i];
    __shared__ double lds[4];
    double w = wave_reduce_d(a);
    int lane = threadIdx.x & 63;
    int wid  = threadIdx.x >> 6;
    if (lane == 0) lds[wid] = w;
    __syncthreads();
    if (threadIdx.x == 0) {
        double total = lds[0] + lds[1] + lds[2] + lds[3];
        out[0] = (float)(total / (double)NTOT);
    }
}

// ---------------------------------------------------------------------------
extern "C" void kernel_launch(void* const* d_in, const int* in_sizes, int n_in,
                              void* d_out, int out_size, void* d_ws, size_t ws_size,
                              hipStream_t stream) {
    const float* x = (const float*)d_in[0];
    const int*   y = (const int*)d_in[1];
    float* out = (float*)d_out;

    unsigned short* g1u = (unsigned short*)d_ws;       // 8*PSTRIDE u16 = 5.25 MB
    double* partials = (double*)((char*)d_ws + (size_t)8 * PSTRIDE * sizeof(unsigned short));
                                                       // 8 KB (1024 doubles), 256B-aligned

    dt_axis3<<<5120, 512, 0, stream>>>(y, g1u);
    dt2_axis0_epilogue<<<PLANE / 256, 256, 0, stream>>>(g1u, x, partials);
    finalize<<<1, 256, 0, stream>>>(partials, out);
}

// Round 2
// 98.917 us; speedup vs baseline: 1.0709x; 1.0709x over previous
//
#include <hip/hip_runtime.h>
#include <math.h>

#define BIGV  1.0e8f
#define PLANE (512 * 512)            // 262144
#define NTOT  (8 * PLANE)            // 2097152
#define PROWS 640                    // 64 pad + 512 + 64 pad
#define PSTRIDE (PROWS * 512)        // ushorts per padded plane
#define HSENT 1023                   // row-DT sentinel: 1023^2 > max real d2

// ---------------------------------------------------------------------------
// Kernel 1: 1-D DT along axis 3 (binary input) via ballot-built 512-bit line
// mask + clz/ffs nearest-set-bit. Writes h (row distance, USHORT — halves the
// HBM write vs f32 h^2) into a PADDED plane layout: row i2 lives at (64+i2);
// rows 0..63 and 576..639 are HSENT pads. Blocks >= 4096 write the pads.
// NO atomics anywhere (device-scope atomics cost ~25 us on gfx950 — measured
// in prior session R5/R8/R9).
// ---------------------------------------------------------------------------
__global__ __launch_bounds__(512) void dt_axis3(const int* __restrict__ y,
                                                unsigned short* __restrict__ g1u) {
    int blk = blockIdx.x;
    if (blk >= 4096) {                                 // pad writer: 1024 blocks
        int idx = (blk - 4096) * 512 + threadIdx.x;    // [0, 524288)
        int plane = idx >> 16;
        int rem   = idx & 65535;
        int r     = rem >> 9;                          // 0..127
        int c     = rem & 511;
        int row   = (r < 64) ? r : (r + 512);          // 0..63 or 576..639
        g1u[plane * PSTRIDE + row * 512 + c] = HSENT;
        return;
    }
    __shared__ unsigned long long words[8];
    int i = threadIdx.x;                               // position in line
    int e = blk * 512 + i;                             // y index (lines contiguous)
    unsigned long long bal = __ballot(y[e] != 0);
    int wid  = i >> 6;
    int lane = i & 63;
    if (lane == 0) words[wid] = bal;
    __syncthreads();

    int k = wid, b = lane;
    int dr = 1 << 30;
    {
        unsigned long long m0 = words[k] & (~0ull << b);
        if (m0) {
            dr = (__ffsll((long long)m0) - 1) - b;
        } else {
            #pragma unroll
            for (int k2 = 0; k2 < 8; ++k2) {
                if (k2 > k && dr == (1 << 30) && words[k2]) {
                    dr = (k2 << 6) + (__ffsll((long long)words[k2]) - 1) - i;
                }
            }
        }
    }
    int dl = 1 << 30;
    {
        unsigned long long m0 = words[k] & (~0ull >> (63 - b));
        if (m0) {
            dl = b - (63 - __clzll((long long)m0));
        } else {
            #pragma unroll
            for (int k2 = 7; k2 >= 0; --k2) {
                if (k2 < k && dl == (1 << 30) && words[k2]) {
                    dl = i - ((k2 << 6) + 63 - __clzll((long long)words[k2]));
                }
            }
        }
    }
    int d = min(dl, dr);
    int h = min(d, HSENT);                             // 0..511 real, 1023 = "row empty"
    int bb = blk >> 9, i2 = blk & 511;
    g1u[bb * PSTRIDE + (64 + i2) * 512 + i] = (unsigned short)h;
}

// ---------------------------------------------------------------------------
// Kernel 2 (FUSED, v2 mapping): thread t of block B owns (batch = t>>5,
// pixel = B*32 + (t&31)). ONE pipelined column scan per thread — identical
// TLP (2M threads, 8192 blocks) to the R7-proven split K2 shape that the
// round-1 fusion destroyed (1024 blocks = 4 waves/CU, 8 serial divergent
// chains/thread → latency-starved, +9 us). D^2 goes through a 32x8 LDS tile
// (stride 9 → bank-conflict-free), then each thread does ITS batch's 8-way
// min-plus + sigmoid + one double term. D2 HBM round-trip (16 MB) deleted.
// ---------------------------------------------------------------------------
__device__ inline double wave_reduce_d(double v) {
    #pragma unroll
    for (int off = 32; off > 0; off >>= 1) v += __shfl_down(v, off, 64);
    return v;
}

__global__ __launch_bounds__(256) void dt2_axis0_epilogue(
        const unsigned short* __restrict__ g1u,
        const float* __restrict__ x,
        double* __restrict__ partials) {
    int t   = threadIdx.x;
    int pix = t & 31;
    int bb  = t >> 5;                                  // batch 0..7
    int s   = blockIdx.x * 32 + pix;                   // spatial [0, PLANE)
    int i2  = s >> 9;                                  // row
    int i3  = s & 511;                                 // col

    const unsigned short* base = g1u + bb * PSTRIDE + (64 + i2) * 512 + i3;
    int h0  = base[0];
    float m = (float)(h0 * h0);                        // exact: <= 1023^2 < 2^24
    int au = base[-512];                               // radius-1 candidates
    int ad = base[+512];
    const unsigned short* up = base - 512;
    const unsigned short* dn = base + 512;
    float fr2 = 1.0f, dstep = 3.0f;                    // r^2: 1,4,9,... exact
    int r = 1;
    for (; r < 64; ++r) {
        if (fr2 >= m) break;                           // uses prev-iter m: safe
        int hm = min(au, ad);
        float cand = (float)(hm * hm) + fr2;           // exact ints < 2^24
        au = up[-512]; ad = dn[+512];                  // prefetch radius r+1
        up -= 512; dn += 512;
        m = fminf(m, cand);                            // pads are HSENT: never win
        fr2 += dstep; dstep += 2.0f;
    }
    if (r == 64) {                                     // ultra-rare exact tail
        for (; r < 512; ++r) {
            float f2 = (float)(r * r);
            if (f2 >= m) break;
            int upr = i2 - r, dnr = i2 + r;
            if (upr < 0 && dnr >= 512) break;
            if (upr >= 0) {
                int hh = g1u[bb * PSTRIDE + (64 + upr) * 512 + i3];
                m = fminf(m, (float)(hh * hh) + f2);
            }
            if (dnr < 512) {
                int hh = g1u[bb * PSTRIDE + (64 + dnr) * 512 + i3];
                m = fminf(m, (float)(hh * hh) + f2);
            }
        }
    }

    // exchange D^2 across batches through LDS (stride 9 → conflict-free: 9 odd)
    __shared__ float vlds[32 * 9];
    vlds[pix * 9 + bb] = m;
    __syncthreads();

    // axis-0 min-plus for OWN batch + sqrt + sigmoid(x)*d, one double term
    float mb = BIGV;
    #pragma unroll
    for (int bp = 0; bp < 8; ++bp) {
        float db = (float)((bb - bp) * (bb - bp));
        mb = fminf(mb, vlds[pix * 9 + bp] + db);
    }
    float xv  = x[bb * PLANE + s];
    float sig = 1.0f / (1.0f + expf(-xv));
    double acc = (double)(sig * sqrtf(mb));

    __shared__ double lds[4];
    double w = wave_reduce_d(acc);
    int lane = threadIdx.x & 63;
    int wid  = threadIdx.x >> 6;
    if (lane == 0) lds[wid] = w;
    __syncthreads();
    if (wid == 0) {
        double tt = (lane < 4) ? lds[lane] : 0.0;
        #pragma unroll
        for (int off = 2; off > 0; off >>= 1) tt += __shfl_down(tt, off, 64);
        if (lane == 0) partials[blockIdx.x] = tt;
    }
}

// ---------------------------------------------------------------------------
// Kernel 3: deterministic final reduce of 8192 block partials. NO atomics.
// ---------------------------------------------------------------------------
__global__ __launch_bounds__(256) void finalize(const double* __restrict__ partials,
                                                float* __restrict__ out) {
    double a = 0.0;
    for (int i = threadIdx.x; i < 8192; i += 256) a += partials[i];
    __shared__ double lds[4];
    double w = wave_reduce_d(a);
    int lane = threadIdx.x & 63;
    int wid  = threadIdx.x >> 6;
    if (lane == 0) lds[wid] = w;
    __syncthreads();
    if (threadIdx.x == 0) {
        double total = lds[0] + lds[1] + lds[2] + lds[3];
        out[0] = (float)(total / (double)NTOT);
    }
}

// ---------------------------------------------------------------------------
extern "C" void kernel_launch(void* const* d_in, const int* in_sizes, int n_in,
                              void* d_out, int out_size, void* d_ws, size_t ws_size,
                              hipStream_t stream) {
    const float* x = (const float*)d_in[0];
    const int*   y = (const int*)d_in[1];
    float* out = (float*)d_out;

    unsigned short* g1u = (unsigned short*)d_ws;       // 8*PSTRIDE u16 = 5.25 MB
    double* partials = (double*)((char*)d_ws + (size_t)8 * PSTRIDE * sizeof(unsigned short));
                                                       // 64 KB (8192 doubles)

    dt_axis3<<<5120, 512, 0, stream>>>(y, g1u);
    dt2_axis0_epilogue<<<PLANE / 32, 256, 0, stream>>>(g1u, x, partials);
    finalize<<<1, 256, 0, stream>>>(partials, out);
}

// Round 3
// 95.037 us; speedup vs baseline: 1.1146x; 1.0408x over previous
//
#include <hip/hip_runtime.h>
#include <math.h>

#define BIGV  1.0e8f
#define PLANE (512 * 512)            // 262144
#define NTOT  (8 * PLANE)            // 2097152
#define PROWS 640                    // 64 pad + 512 + 64 pad
#define PSTRIDE (PROWS * 512)        // ushorts per padded plane
#define HSENT 1023                   // row-DT sentinel: 1023^2 > max real d2

// ---------------------------------------------------------------------------
// Kernel 1: 1-D DT along axis 3 (binary input) via ballot-built 512-bit line
// mask + clz/ffs nearest-set-bit. Writes h (row distance, USHORT) into a
// PADDED plane layout: row i2 lives at (64+i2); rows 0..63 and 576..639 are
// HSENT pads. Blocks >= 4096 write the pads. NO atomics anywhere.
// ---------------------------------------------------------------------------
__global__ __launch_bounds__(512) void dt_axis3(const int* __restrict__ y,
                                                unsigned short* __restrict__ g1u) {
    int blk = blockIdx.x;
    if (blk >= 4096) {                                 // pad writer: 1024 blocks
        int idx = (blk - 4096) * 512 + threadIdx.x;    // [0, 524288)
        int plane = idx >> 16;
        int rem   = idx & 65535;
        int r     = rem >> 9;                          // 0..127
        int c     = rem & 511;
        int row   = (r < 64) ? r : (r + 512);          // 0..63 or 576..639
        g1u[plane * PSTRIDE + row * 512 + c] = HSENT;
        return;
    }
    __shared__ unsigned long long words[8];
    int i = threadIdx.x;                               // position in line
    int e = blk * 512 + i;                             // y index (lines contiguous)
    unsigned long long bal = __ballot(y[e] != 0);
    int wid  = i >> 6;
    int lane = i & 63;
    if (lane == 0) words[wid] = bal;
    __syncthreads();

    int k = wid, b = lane;
    int dr = 1 << 30;
    {
        unsigned long long m0 = words[k] & (~0ull << b);
        if (m0) {
            dr = (__ffsll((long long)m0) - 1) - b;
        } else {
            #pragma unroll
            for (int k2 = 0; k2 < 8; ++k2) {
                if (k2 > k && dr == (1 << 30) && words[k2]) {
                    dr = (k2 << 6) + (__ffsll((long long)words[k2]) - 1) - i;
                }
            }
        }
    }
    int dl = 1 << 30;
    {
        unsigned long long m0 = words[k] & (~0ull >> (63 - b));
        if (m0) {
            dl = b - (63 - __clzll((long long)m0));
        } else {
            #pragma unroll
            for (int k2 = 7; k2 >= 0; --k2) {
                if (k2 < k && dl == (1 << 30) && words[k2]) {
                    dl = i - ((k2 << 6) + 63 - __clzll((long long)words[k2]));
                }
            }
        }
    }
    int d = min(dl, dr);
    int h = min(d, HSENT);                             // 0..511 real, 1023 = "row empty"
    int bb = blk >> 9, i2 = blk & 511;
    g1u[bb * PSTRIDE + (64 + i2) * 512 + i] = (unsigned short)h;
}

// ---------------------------------------------------------------------------
// Kernel 2 (FUSED, v3 mapping — wave==batch): 512-thread block B owns 64
// CONSECUTIVE pixels (one row segment; 64 | 512 so never crosses a row) x all
// 8 batches. Wave w scans batch w for its 64 pixels: every scan load is 64
// lanes x 2 B CONTIGUOUS = one 128 B segment (R2's t&31 mapping split every
// wave across 2 batches = 2 scattered 64 B segments — the suspected 3-5 us
// regression). Waves are spatially-coherent within one batch → correlated
// scan lengths → less divergence. D^2 exchanged via stride-9 LDS
// (conflict-free), then each thread does ITS batch's 8-way min-plus +
// sigmoid + one double term. No D2 HBM round-trip. Grid 4096 x 8 waves =
// 32768 waves (same TLP as the R7-proven split K2).
// ---------------------------------------------------------------------------
__device__ inline double wave_reduce_d(double v) {
    #pragma unroll
    for (int off = 32; off > 0; off >>= 1) v += __shfl_down(v, off, 64);
    return v;
}

__global__ __launch_bounds__(512) void dt2_axis0_epilogue(
        const unsigned short* __restrict__ g1u,
        const float* __restrict__ x,
        double* __restrict__ partials) {
    int t   = threadIdx.x;
    int pix = t & 63;                                  // pixel offset in block
    int bb  = t >> 6;                                  // wave index == batch 0..7
    int s   = blockIdx.x * 64 + pix;                   // spatial [0, PLANE)
    int i2  = s >> 9;                                  // row (constant per block)
    int i3  = s & 511;                                 // col

    const unsigned short* base = g1u + bb * PSTRIDE + (64 + i2) * 512 + i3;
    int h0  = base[0];
    float m = (float)(h0 * h0);                        // exact: <= 1023^2 < 2^24
    int au = base[-512];                               // radius-1 candidates
    int ad = base[+512];
    const unsigned short* up = base - 512;
    const unsigned short* dn = base + 512;
    float fr2 = 1.0f, dstep = 3.0f;                    // r^2: 1,4,9,... exact
    int r = 1;
    for (; r < 64; ++r) {
        if (fr2 >= m) break;                           // uses prev-iter m: safe
        int hm = min(au, ad);
        float cand = (float)(hm * hm) + fr2;           // exact ints < 2^24
        au = up[-512]; ad = dn[+512];                  // prefetch radius r+1
        up -= 512; dn += 512;
        m = fminf(m, cand);                            // pads are HSENT: never win
        fr2 += dstep; dstep += 2.0f;
    }
    if (r == 64) {                                     // ultra-rare exact tail
        for (; r < 512; ++r) {
            float f2 = (float)(r * r);
            if (f2 >= m) break;
            int upr = i2 - r, dnr = i2 + r;
            if (upr < 0 && dnr >= 512) break;
            if (upr >= 0) {
                int hh = g1u[bb * PSTRIDE + (64 + upr) * 512 + i3];
                m = fminf(m, (float)(hh * hh) + f2);
            }
            if (dnr < 512) {
                int hh = g1u[bb * PSTRIDE + (64 + dnr) * 512 + i3];
                m = fminf(m, (float)(hh * hh) + f2);
            }
        }
    }

    // exchange D^2 across batches through LDS (stride 9 floats: 9 odd →
    // bank pattern (9p+bb)&31 covers all banks per 32-lane group → no conflict)
    __shared__ float vlds[64 * 9];
    vlds[pix * 9 + bb] = m;
    __syncthreads();

    // axis-0 min-plus for OWN batch + sqrt + sigmoid(x)*d, one double term
    float mb = BIGV;
    #pragma unroll
    for (int bp = 0; bp < 8; ++bp) {
        float db = (float)((bb - bp) * (bb - bp));
        mb = fminf(mb, vlds[pix * 9 + bp] + db);
    }
    float xv  = x[bb * PLANE + s];                     // 256 B/wave, coalesced
    float sig = 1.0f / (1.0f + expf(-xv));
    double acc = (double)(sig * sqrtf(mb));

    __shared__ double lds[8];
    double w = wave_reduce_d(acc);
    int lane = t & 63;
    if (lane == 0) lds[bb] = w;
    __syncthreads();
    if (bb == 0) {
        double tt = (lane < 8) ? lds[lane] : 0.0;
        #pragma unroll
        for (int off = 4; off > 0; off >>= 1) tt += __shfl_down(tt, off, 64);
        if (lane == 0) partials[blockIdx.x] = tt;
    }
}

// ---------------------------------------------------------------------------
// Kernel 3: deterministic final reduce of 4096 block partials. NO atomics.
// ---------------------------------------------------------------------------
__global__ __launch_bounds__(256) void finalize(const double* __restrict__ partials,
                                                float* __restrict__ out) {
    double a = 0.0;
    for (int i = threadIdx.x; i < 4096; i += 256) a += partials[i];
    __shared__ double lds[4];
    double w = wave_reduce_d(a);
    int lane = threadIdx.x & 63;
    int wid  = threadIdx.x >> 6;
    if (lane == 0) lds[wid] = w;
    __syncthreads();
    if (threadIdx.x == 0) {
        double total = lds[0] + lds[1] + lds[2] + lds[3];
        out[0] = (float)(total / (double)NTOT);
    }
}

// ---------------------------------------------------------------------------
extern "C" void kernel_launch(void* const* d_in, const int* in_sizes, int n_in,
                              void* d_out, int out_size, void* d_ws, size_t ws_size,
                              hipStream_t stream) {
    const float* x = (const float*)d_in[0];
    const int*   y = (const int*)d_in[1];
    float* out = (float*)d_out;

    unsigned short* g1u = (unsigned short*)d_ws;       // 8*PSTRIDE u16 = 5.25 MB
    double* partials = (double*)((char*)d_ws + (size_t)8 * PSTRIDE * sizeof(unsigned short));
                                                       // 32 KB (4096 doubles)

    dt_axis3<<<5120, 512, 0, stream>>>(y, g1u);
    dt2_axis0_epilogue<<<PLANE / 64, 512, 0, stream>>>(g1u, x, partials);
    finalize<<<1, 256, 0, stream>>>(partials, out);
}